// Round 1
// baseline (16.081 us; speedup 1.0000x reference)
//
#include <hip/hip_runtime.h>
#include <math.h>

// PoincareMLR: logits[b,k] = asinh(2*<diff,a>/clamp_abs((1-|diff|^2)*|a|)) * |a|
// with diff = mobius_add(-expmap0(point_k), x_b), c=1.
// Algebraic reduction: expmap0(point) = cc*point (cc scalar per k), so everything
// reduces to s = cc*<point_k,x_b>, t = <a_k,x_b>, U2=|x_b|^2, P2=cc^2|point_k|^2,
// PA=cc*<point_k,a_k>, AN=|a_k|:
//   alpha = 1-2s+U2, beta = 1-P2, gamma = max(1-2s+P2*U2, EPS)
//   |diff|^2 = (alpha^2*P2 - 2*alpha*beta*s + beta^2*U2)/gamma^2
//   <diff,a> = (beta*t - alpha*PA)/gamma

constexpr int D      = 256;   // feature dim
constexpr int Dv     = 64;    // float4 per row
constexpr int KTOT   = 128;   // outcomes
constexpr int BTILE  = 32;    // b-rows per block
constexpr int KTILE  = 16;    // k-rows per block
constexpr int NKB    = KTOT / KTILE;  // 8 k-tiles
constexpr int STRIDE = 260;   // LDS row stride in floats (+4 pad, 16B aligned)
constexpr float EPS  = 1e-15f;

__device__ __forceinline__ float dot4(float4 a, float4 b) {
    return a.x * b.x + a.y * b.y + a.z * b.z + a.w * b.w;
}

__device__ __forceinline__ float epilogue(float s_raw, float t_raw, float U2,
                                          float cc, float P2, float PA, float AN) {
    float s     = cc * s_raw;
    float alpha = 1.f - 2.f * s + U2;
    float beta  = 1.f - P2;
    float gamma = fmaxf(1.f - 2.f * s + P2 * U2, EPS);
    float nn    = alpha * alpha * P2 - 2.f * alpha * beta * s + beta * beta * U2;
    float dn2   = fmaxf(nn / (gamma * gamma), EPS);
    float sc    = (beta * t_raw - alpha * PA) / gamma;
    float draw  = (1.f - dn2) * AN;
    float den   = (draw >= 0.f ? 1.f : -1.f) * fmaxf(fabsf(draw), EPS);
    return asinhf(2.f * sc / den) * AN;
}

__global__ __launch_bounds__(256, 2)
void poincare_mlr_kernel(const float* __restrict__ X,   // [B, D]
                         const float* __restrict__ P,   // [K, D] point
                         const float* __restrict__ A,   // [K, D] tangent
                         float* __restrict__ out,       // [B, K]
                         int K) {
    extern __shared__ float lds[];
    float* xs  = lds;                       // [BTILE][STRIDE]
    float* ps  = xs + BTILE * STRIDE;       // [KTILE][STRIDE]
    float* as_ = ps + KTILE * STRIDE;       // [KTILE][STRIDE]
    __shared__ float U2s[BTILE];
    __shared__ float kcc[KTILE], kP2[KTILE], kPA[KTILE], kAN[KTILE];

    const int tid = threadIdx.x;
    const int kb  = blockIdx.x & (NKB - 1);
    const int bb  = blockIdx.x >> 3;        // log2(NKB) = 3
    const int b0g = bb * BTILE;
    const int k0g = kb * KTILE;

    // ---- stage tiles into LDS (coalesced float4) ----
    const float4* Xg = (const float4*)(X + (size_t)b0g * D);
    for (int i = tid; i < BTILE * Dv; i += 256) {
        int r = i >> 6, c = i & 63;
        *(float4*)&xs[r * STRIDE + 4 * c] = Xg[r * Dv + c];
    }
    const float4* Pg = (const float4*)(P + (size_t)k0g * D);
    const float4* Ag = (const float4*)(A + (size_t)k0g * D);
    for (int i = tid; i < KTILE * Dv; i += 256) {
        int r = i >> 6, c = i & 63;
        *(float4*)&ps[r * STRIDE + 4 * c]  = Pg[r * Dv + c];
        *(float4*)&as_[r * STRIDE + 4 * c] = Ag[r * Dv + c];
    }
    __syncthreads();

    // ---- per-b row norms: 8 threads per row ----
    {
        int r = tid >> 3, g = tid & 7;
        const float* xr = &xs[r * STRIDE];
        float v = 0.f;
        #pragma unroll
        for (int t = 0; t < 8; ++t) {
            float4 x4 = *(const float4*)&xr[4 * (g + 8 * t)];
            v += dot4(x4, x4);
        }
        #pragma unroll
        for (int off = 4; off; off >>= 1) v += __shfl_down(v, off, 8);
        if (g == 0) U2s[r] = v;
    }
    // ---- per-k scalars: 16 threads per row ----
    {
        int r = tid >> 4, g = tid & 15;
        const float* pr = &ps[r * STRIDE];
        const float* ar = &as_[r * STRIDE];
        float n2 = 0.f, pa = 0.f, a2 = 0.f;
        #pragma unroll
        for (int t = 0; t < 4; ++t) {
            float4 p4 = *(const float4*)&pr[4 * (g + 16 * t)];
            float4 a4 = *(const float4*)&ar[4 * (g + 16 * t)];
            n2 += dot4(p4, p4);
            pa += dot4(p4, a4);
            a2 += dot4(a4, a4);
        }
        #pragma unroll
        for (int off = 8; off; off >>= 1) {
            n2 += __shfl_down(n2, off, 16);
            pa += __shfl_down(pa, off, 16);
            a2 += __shfl_down(a2, off, 16);
        }
        if (g == 0) {
            float n  = sqrtf(n2);
            float un = fmaxf(n, EPS);          // geoopt clamp
            float cc = tanhf(un) / un;         // expmap0 scale: p = cc*point
            kcc[r] = cc;
            kP2[r] = cc * cc * n2;
            kPA[r] = cc * pa;
            kAN[r] = sqrtf(a2);
        }
    }
    __syncthreads();

    // ---- main dot products: thread = (k=tx, b rows ty and ty+16) ----
    const int tx = tid & 15, ty = tid >> 4;
    const float* pr = &ps[tx * STRIDE];
    const float* ar = &as_[tx * STRIDE];
    const float* x0 = &xs[ty * STRIDE];
    const float* x1 = &xs[(ty + 16) * STRIDE];
    float s0 = 0.f, s1 = 0.f, t0 = 0.f, t1 = 0.f;
    #pragma unroll 8
    for (int c = 0; c < Dv; ++c) {
        float4 p4 = *(const float4*)&pr[4 * c];
        float4 a4 = *(const float4*)&ar[4 * c];
        float4 xa = *(const float4*)&x0[4 * c];
        float4 xb = *(const float4*)&x1[4 * c];
        s0 += dot4(xa, p4);
        t0 += dot4(xa, a4);
        s1 += dot4(xb, p4);
        t1 += dot4(xb, a4);
    }

    const float cc = kcc[tx], P2 = kP2[tx], PA = kPA[tx], AN = kAN[tx];
    const int kg = k0g + tx;
    out[(size_t)(b0g + ty) * K + kg]        = epilogue(s0, t0, U2s[ty],      cc, P2, PA, AN);
    out[(size_t)(b0g + ty + 16) * K + kg]   = epilogue(s1, t1, U2s[ty + 16], cc, P2, PA, AN);
}

extern "C" void kernel_launch(void* const* d_in, const int* in_sizes, int n_in,
                              void* d_out, int out_size, void* d_ws, size_t ws_size,
                              hipStream_t stream) {
    const float* X = (const float*)d_in[0];   // input  [B, 256]
    const float* P = (const float*)d_in[1];   // point  [128, 256]
    const float* A = (const float*)d_in[2];   // tangent[128, 256]
    float* out = (float*)d_out;

    const int B = in_sizes[0] / D;            // 2048
    const int K = in_sizes[1] / D;            // 128

    const int nb = B / BTILE;                 // 64
    dim3 grid(nb * NKB);                      // 512 blocks
    size_t lds_bytes = (size_t)(BTILE + 2 * KTILE) * STRIDE * sizeof(float); // 66560
    poincare_mlr_kernel<<<grid, dim3(256), lds_bytes, stream>>>(X, P, A, out, K);
}

// Round 2
// 11.229 us; speedup vs baseline: 1.4320x; 1.4320x over previous
//
#include <hip/hip_runtime.h>
#include <math.h>

// PoincareMLR via algebraic reduction + bf16 MFMA for the two batched dots.
//   s_raw = <point_k, x_b>, t = <a_k, x_b>   (MFMA, bf16 in / f32 acc)
//   U2=|x_b|^2, cc=tanh(|point|)/|point|, P2=cc^2|point|^2, PA=cc<point,a>, AN=|a|  (fp32)
//   alpha=1-2s+U2, beta=1-P2, gamma=max(1-2s+P2*U2,EPS), s=cc*s_raw
//   |diff|^2=(alpha^2 P2 - 2 alpha beta s + beta^2 U2)/gamma^2
//   <diff,a>=(beta t - alpha PA)/gamma
//   logit = asinh(2<diff,a>/clamp_abs((1-|diff|^2)AN)) * AN

constexpr int D    = 256;   // feature dim
constexpr int Dv   = 64;    // float4 per row
constexpr int BT   = 32;    // b rows per block
constexpr int KT   = 32;    // k rows per block
constexpr int S    = 264;   // LDS row stride in bf16 (+16B pad -> conflict-free b128 reads)
constexpr float EPS = 1e-15f;

typedef __attribute__((ext_vector_type(8))) short short8;
typedef __attribute__((ext_vector_type(4))) float f32x4;

__device__ __forceinline__ ushort f2bf(float f) {
    uint u = __float_as_uint(f);
    u += 0x7FFFu + ((u >> 16) & 1u);          // round-to-nearest-even
    return (ushort)(u >> 16);
}

__device__ __forceinline__ float dot4(float4 a, float4 b) {
    return a.x * b.x + a.y * b.y + a.z * b.z + a.w * b.w;
}

__device__ __forceinline__ float epilogue(float s_raw, float t_raw, float U2,
                                          float cc, float P2, float PA, float AN) {
    float s     = cc * s_raw;
    float alpha = 1.f - 2.f * s + U2;
    float beta  = 1.f - P2;
    float gamma = fmaxf(1.f - 2.f * s + P2 * U2, EPS);
    float nn    = alpha * alpha * P2 - 2.f * alpha * beta * s + beta * beta * U2;
    float dn2   = fmaxf(nn / (gamma * gamma), EPS);
    float sc    = (beta * t_raw - alpha * PA) / gamma;
    float draw  = (1.f - dn2) * AN;
    float den   = (draw >= 0.f ? 1.f : -1.f) * fmaxf(fabsf(draw), EPS);
    return asinhf(2.f * sc / den) * AN;
}

__global__ __launch_bounds__(256)
void poincare_mlr_kernel(const float* __restrict__ X,   // [B, D]
                         const float* __restrict__ P,   // [K, D] point
                         const float* __restrict__ A,   // [K, D] tangent
                         float* __restrict__ out,       // [B, K]
                         int K) {
    __shared__ ushort xs[BT * S];
    __shared__ ushort ps[KT * S];
    __shared__ ushort as_[KT * S];
    __shared__ float U2s[BT];
    __shared__ float kcc[KT], kP2[KT], kPA[KT], kAN[KT];

    const int tid = threadIdx.x;
    const int kb  = blockIdx.x & 3;          // K/KT = 4 k-tiles
    const int bb  = blockIdx.x >> 2;
    const int b0g = bb * BT;
    const int k0g = kb * KT;

    // ---- stage tiles to LDS as bf16 (coalesced float4 loads, 8B LDS stores) ----
    const float4* Xg = (const float4*)(X + (size_t)b0g * D);
    const float4* Pg = (const float4*)(P + (size_t)k0g * D);
    const float4* Ag = (const float4*)(A + (size_t)k0g * D);
    #pragma unroll
    for (int it = 0; it < 8; ++it) {
        int i = tid + 256 * it;              // BT*Dv = 2048 float4 per tile
        int r = i >> 6, g = i & 63;
        float4 vx = Xg[r * Dv + g];
        float4 vp = Pg[r * Dv + g];
        float4 va = Ag[r * Dv + g];
        ushort4 bx = make_ushort4(f2bf(vx.x), f2bf(vx.y), f2bf(vx.z), f2bf(vx.w));
        ushort4 bp = make_ushort4(f2bf(vp.x), f2bf(vp.y), f2bf(vp.z), f2bf(vp.w));
        ushort4 ba = make_ushort4(f2bf(va.x), f2bf(va.y), f2bf(va.z), f2bf(va.w));
        *(ushort4*)&xs[r * S + 4 * g]  = bx;
        *(ushort4*)&ps[r * S + 4 * g]  = bp;
        *(ushort4*)&as_[r * S + 4 * g] = ba;
    }

    // ---- per-b row norms from GLOBAL fp32 (8 threads per row) ----
    {
        int r = tid >> 3, g = tid & 7;
        const float4* xr = Xg + (size_t)r * Dv;
        float v = 0.f;
        #pragma unroll
        for (int t = 0; t < 8; ++t) {
            float4 x4 = xr[g + 8 * t];
            v += dot4(x4, x4);
        }
        #pragma unroll
        for (int off = 4; off; off >>= 1) v += __shfl_down(v, off, 8);
        if (g == 0) U2s[r] = v;
    }
    // ---- per-k scalars from GLOBAL fp32 (8 threads per row) ----
    {
        int r = tid >> 3, g = tid & 7;
        const float4* pr = Pg + (size_t)r * Dv;
        const float4* ar = Ag + (size_t)r * Dv;
        float n2 = 0.f, pa = 0.f, a2 = 0.f;
        #pragma unroll
        for (int t = 0; t < 8; ++t) {
            float4 p4 = pr[g + 8 * t];
            float4 a4 = ar[g + 8 * t];
            n2 += dot4(p4, p4);
            pa += dot4(p4, a4);
            a2 += dot4(a4, a4);
        }
        #pragma unroll
        for (int off = 4; off; off >>= 1) {
            n2 += __shfl_down(n2, off, 8);
            pa += __shfl_down(pa, off, 8);
            a2 += __shfl_down(a2, off, 8);
        }
        if (g == 0) {
            float n  = sqrtf(n2);
            float un = fmaxf(n, EPS);
            float cc = tanhf(un) / un;       // expmap0 scale: p = cc*point
            kcc[r] = cc;
            kP2[r] = cc * cc * n2;
            kPA[r] = cc * pa;
            kAN[r] = sqrtf(a2);
        }
    }
    __syncthreads();

    // ---- MFMA: wave w covers (wb*16 b-rows) x (wk*16 k-cols), Kdim=256 in 8 steps ----
    const int lane = tid & 63, wv = tid >> 6;
    const int wb = wv >> 1, wk = wv & 1;
    const int m  = lane & 15, kq = lane >> 4;  // A/B frag: row/col = lane&15, kslice = lane>>4

    const ushort* xb = xs  + (size_t)(wb * 16 + m) * S + kq * 8;
    const ushort* pb = ps  + (size_t)(wk * 16 + m) * S + kq * 8;
    const ushort* ab = as_ + (size_t)(wk * 16 + m) * S + kq * 8;

    f32x4 accS = {0.f, 0.f, 0.f, 0.f};
    f32x4 accT = {0.f, 0.f, 0.f, 0.f};
    #pragma unroll
    for (int st = 0; st < 8; ++st) {
        short8 xa = *(const short8*)(xb + st * 32);
        short8 pf = *(const short8*)(pb + st * 32);
        short8 af = *(const short8*)(ab + st * 32);
        accS = __builtin_amdgcn_mfma_f32_16x16x32_bf16(xa, pf, accS, 0, 0, 0);
        accT = __builtin_amdgcn_mfma_f32_16x16x32_bf16(xa, af, accT, 0, 0, 0);
    }

    // ---- epilogue: lane holds C[row=(kq*4+j)][col=m] for its wave tile ----
    const int kloc = wk * 16 + m;
    const float cc = kcc[kloc], P2 = kP2[kloc], PA = kPA[kloc], AN = kAN[kloc];
    const int kg = k0g + kloc;
    #pragma unroll
    for (int j = 0; j < 4; ++j) {
        int rloc = wb * 16 + kq * 4 + j;
        out[(size_t)(b0g + rloc) * K + kg] =
            epilogue(accS[j], accT[j], U2s[rloc], cc, P2, PA, AN);
    }
}

extern "C" void kernel_launch(void* const* d_in, const int* in_sizes, int n_in,
                              void* d_out, int out_size, void* d_ws, size_t ws_size,
                              hipStream_t stream) {
    const float* X = (const float*)d_in[0];   // input  [B, 256]
    const float* P = (const float*)d_in[1];   // point  [128, 256]
    const float* A = (const float*)d_in[2];   // tangent[128, 256]
    float* out = (float*)d_out;

    const int B = in_sizes[0] / D;            // 2048
    const int K = in_sizes[1] / D;            // 128

    dim3 grid((B / BT) * (K / KT));           // 64 * 4 = 256 blocks
    poincare_mlr_kernel<<<grid, dim3(256), 0, stream>>>(X, P, A, out, K);
}

// Round 3
// 10.181 us; speedup vs baseline: 1.5795x; 1.1029x over previous
//
#include <hip/hip_runtime.h>
#include <math.h>

// PoincareMLR via algebraic reduction + bf16 MFMA for the two batched dots.
//   s_raw = <point_k, x_b>, t = <a_k, x_b>   (MFMA, bf16 in / f32 acc)
//   U2=|x_b|^2, cc=tanh(|point|)/|point|, P2=cc^2|point|^2, PA=cc<point,a>, AN=|a|  (fp32)
//   alpha=1-2s+U2, beta=1-P2, gamma=max(1-2s+P2*U2,EPS), s=cc*s_raw
//   |diff|^2=(alpha^2 P2 - 2 alpha beta s + beta^2 U2)/gamma^2
//   <diff,a>=(beta t - alpha PA)/gamma
//   logit = asinh(2<diff,a>/clamp_abs((1-|diff|^2)AN)) * AN
//
// R3: 512-thread blocks (2 waves/SIMD TLP), staging fused with per-row scalar
// reductions (single global read), fast asinh/tanh epilogue, 8 waves duplicate
// the 4 MFMA tiles and split the epilogue by accumulator half.

constexpr int D   = 256;   // feature dim
constexpr int BT  = 32;    // b rows per block
constexpr int KT  = 32;    // k rows per block
constexpr int S   = 264;   // LDS row stride in bf16 (+16B pad -> conflict-free b128)
constexpr float EPS = 1e-15f;

typedef __attribute__((ext_vector_type(8))) short short8;
typedef __attribute__((ext_vector_type(4))) float f32x4;

__device__ __forceinline__ ushort f2bf(float f) {
    uint u = __float_as_uint(f);
    u += 0x7FFFu + ((u >> 16) & 1u);          // round-to-nearest-even
    return (ushort)(u >> 16);
}
__device__ __forceinline__ ushort4 bf4(float4 v) {
    return make_ushort4(f2bf(v.x), f2bf(v.y), f2bf(v.z), f2bf(v.w));
}
__device__ __forceinline__ float dot4(float4 a, float4 b) {
    return a.x * b.x + a.y * b.y + a.z * b.z + a.w * b.w;
}

__device__ __forceinline__ float epilogue(float s_raw, float t_raw, float U2,
                                          float cc, float P2, float PA, float AN) {
    float s     = cc * s_raw;
    float alpha = 1.f - 2.f * s + U2;
    float beta  = 1.f - P2;
    float gamma = fmaxf(1.f - 2.f * s + P2 * U2, EPS);
    float rg    = __builtin_amdgcn_rcpf(gamma);
    float nn    = alpha * alpha * P2 - 2.f * alpha * beta * s + beta * beta * U2;
    float dn2   = fmaxf(nn * rg * rg, EPS);
    float sc    = (beta * t_raw - alpha * PA) * rg;
    float draw  = (1.f - dn2) * AN;
    float den   = (draw >= 0.f ? 1.f : -1.f) * fmaxf(fabsf(draw), EPS);
    float z     = 2.f * sc * __builtin_amdgcn_rcpf(den);
    float az    = fabsf(z);
    // asinh(az) = log2(az + sqrt(az^2+1)) * ln2
    float r = __builtin_amdgcn_logf(az + __builtin_amdgcn_sqrtf(__builtin_fmaf(az, az, 1.f)))
              * 0.6931471805599453f;
    return (z >= 0.f ? r : -r) * AN;
}

__global__ __launch_bounds__(512, 2)
void poincare_mlr_kernel(const float* __restrict__ X,   // [B, D]
                         const float* __restrict__ P,   // [K, D] point
                         const float* __restrict__ A,   // [K, D] tangent
                         float* __restrict__ out,       // [B, K]
                         int K) {
    __shared__ ushort xs[BT * S];
    __shared__ ushort ps[KT * S];
    __shared__ ushort as_[KT * S];
    __shared__ float U2s[BT];
    __shared__ float kcc[KT], kP2[KT], kPA[KT], kAN[KT];

    const int tid = threadIdx.x;
    const int kb  = blockIdx.x & 3;          // K/KT = 4 k-tiles
    const int bb  = blockIdx.x >> 2;
    const int b0g = bb * BT;
    const int k0g = kb * KT;

    // ---- fused staging + per-row scalars ----
    // thread (rx, g): rx = tid>>4 in [0,32), g = tid&15. Owns 4 float4 chunks
    // (cols g+16t) of X row rx, P row rx, A row rx. Converts to bf16 LDS and
    // accumulates x.x, p.p, p.a, a.a along the way. Single global read.
    {
        const int rx = tid >> 4, g = tid & 15;
        const float4* Xr = (const float4*)(X + (size_t)(b0g + rx) * D);
        const float4* Pr = (const float4*)(P + (size_t)(k0g + rx) * D);
        const float4* Ar = (const float4*)(A + (size_t)(k0g + rx) * D);
        float x2 = 0.f, n2 = 0.f, pa = 0.f, a2 = 0.f;
        #pragma unroll
        for (int t = 0; t < 4; ++t) {
            const int c = g + 16 * t;
            float4 vx = Xr[c];
            float4 vp = Pr[c];
            float4 va = Ar[c];
            x2 += dot4(vx, vx);
            n2 += dot4(vp, vp);
            pa += dot4(vp, va);
            a2 += dot4(va, va);
            *(ushort4*)&xs[rx * S + 4 * c]  = bf4(vx);
            *(ushort4*)&ps[rx * S + 4 * c]  = bf4(vp);
            *(ushort4*)&as_[rx * S + 4 * c] = bf4(va);
        }
        #pragma unroll
        for (int off = 8; off; off >>= 1) {
            x2 += __shfl_xor(x2, off, 16);
            n2 += __shfl_xor(n2, off, 16);
            pa += __shfl_xor(pa, off, 16);
            a2 += __shfl_xor(a2, off, 16);
        }
        if (g == 0) {
            U2s[rx] = x2;
            float un = fmaxf(__builtin_amdgcn_sqrtf(n2), EPS);
            float u2 = un * un;
            // tanh(un)/un, un ~ 0.016: series (err ~1e-8); guarded fallback
            float cc = 1.f - u2 * (1.f / 3.f) + u2 * u2 * (2.f / 15.f);
            if (un > 0.04f) cc = tanhf(un) / un;
            kcc[rx] = cc;
            kP2[rx] = cc * cc * n2;
            kPA[rx] = cc * pa;
            kAN[rx] = __builtin_amdgcn_sqrtf(a2);
        }
    }
    __syncthreads();

    // ---- MFMA: 8 waves, 4 output tiles (wb,wk), duplicate pairs split the
    // epilogue by accumulator half jh. Kdim = 256 in 8 steps. ----
    const int lane = tid & 63, wv = tid >> 6;
    const int wb = wv & 1, wk = (wv >> 1) & 1, jh = wv >> 2;
    const int m  = lane & 15, kq = lane >> 4;

    const ushort* xb = xs  + (size_t)(wb * 16 + m) * S + kq * 8;
    const ushort* pb = ps  + (size_t)(wk * 16 + m) * S + kq * 8;
    const ushort* ab = as_ + (size_t)(wk * 16 + m) * S + kq * 8;

    f32x4 accS = {0.f, 0.f, 0.f, 0.f};
    f32x4 accT = {0.f, 0.f, 0.f, 0.f};
    #pragma unroll
    for (int st = 0; st < 8; ++st) {
        short8 xa = *(const short8*)(xb + st * 32);
        short8 pf = *(const short8*)(pb + st * 32);
        short8 af = *(const short8*)(ab + st * 32);
        accS = __builtin_amdgcn_mfma_f32_16x16x32_bf16(xa, pf, accS, 0, 0, 0);
        accT = __builtin_amdgcn_mfma_f32_16x16x32_bf16(xa, af, accT, 0, 0, 0);
    }

    // constant-index extraction of this wave's accumulator half (no scratch)
    const float sA = jh ? accS[2] : accS[0];
    const float tA = jh ? accT[2] : accT[0];
    const float sB = jh ? accS[3] : accS[1];
    const float tB = jh ? accT[3] : accT[1];

    const int kloc = wk * 16 + m;
    const float cc = kcc[kloc], P2 = kP2[kloc], PA = kPA[kloc], AN = kAN[kloc];
    const int kg = k0g + kloc;
    const int r0 = wb * 16 + kq * 4 + jh * 2;   // rows jh*2 and jh*2+1 of the frag

    out[(size_t)(b0g + r0) * K + kg]     = epilogue(sA, tA, U2s[r0],     cc, P2, PA, AN);
    out[(size_t)(b0g + r0 + 1) * K + kg] = epilogue(sB, tB, U2s[r0 + 1], cc, P2, PA, AN);
}

extern "C" void kernel_launch(void* const* d_in, const int* in_sizes, int n_in,
                              void* d_out, int out_size, void* d_ws, size_t ws_size,
                              hipStream_t stream) {
    const float* X = (const float*)d_in[0];   // input  [B, 256]
    const float* P = (const float*)d_in[1];   // point  [128, 256]
    const float* A = (const float*)d_in[2];   // tangent[128, 256]
    float* out = (float*)d_out;

    const int B = in_sizes[0] / D;            // 2048
    const int K = in_sizes[1] / D;            // 128

    dim3 grid((B / BT) * (K / KT));           // 64 * 4 = 256 blocks
    poincare_mlr_kernel<<<grid, dim3(512), 0, stream>>>(X, P, A, out, K);
}